// Round 2
// baseline (449.046 us; speedup 1.0000x reference)
//
#include <hip/hip_runtime.h>

// ---------------------------------------------------------------------------
// IDynamicDWConv pipeline, fp32 end-to-end.
// R10: dispatch-slot reduction 27 -> 15. R9's null result (+-0.1% for a +-30%
//     kernel-work change) shows the wall is ~13.8us per dispatch slot, not
//     kernel time. So: kill the K-split+combine structure. conv3x3f_k does
//     the FULL ci=64 reduction in one 512-thr block (8 waves = 4 oc-quads x
//     2 ci-halves, tile 8x16, lane = 2px x 4oc, LDS cross-wave combine) and
//     fuses the epilogue (bias+lrelu / bias+res / bias+res+maxpool2 via
//     shfl_xor). Weights via wave-uniform scalar path. Partial buffers gone.
// avgpool / conv1x1 / dynconv unchanged (R7/R8-verified).
// ---------------------------------------------------------------------------

__global__ __launch_bounds__(256) void avgpool4_k(const float* __restrict__ x,
                                                  float* __restrict__ y) {
    int idx = blockIdx.x * 256 + threadIdx.x;      // 524288
    int wo = idx & 63;
    int ho = (idx >> 6) & 63;
    int cz = idx >> 12;
    const float* base = x + ((long)cz * 256 + ho * 4) * 256 + wo * 4;
    float s = 0.f;
#pragma unroll
    for (int r = 0; r < 4; ++r) {
        float4 v = *(const float4*)(base + r * 256);
        s += v.x + v.y + v.z + v.w;
    }
    y[idx] = s * 0.0625f;
}

// Fused full-CI 3x3 conv (zero-pad SAME) + epilogue.
// Block: 512 thr = 8 waves = 4 oc-quads x 2 ci-halves; tile 8x16 px;
// lane = 2 w-px x 4 oc (lx = strip 0..7, ly = row 0..7).
// VAR: 0 = bias+lrelu; 1 = bias+res; 2 = bias+res+maxpool2 (writes S/2 grid).
template <int S, int VAR>
__global__ __launch_bounds__(512) void conv3x3f_k(
    const float* __restrict__ in, const float* __restrict__ wgt,
    const float* __restrict__ bias, const float* __restrict__ res,
    float* __restrict__ outp) {
    constexpr int TH = 8, TW = 16;
    constexpr int NTW = S / TW, NTH = S / TH;
    constexpr int NT = NTW * NTH;
    constexpr int SROW = 20;                       // padded row stride
    constexpr int CHW = 10 * SROW;                 // 200 floats per channel
    constexpr int TOTS = 16 * 10 * 18;             // 2880 staged elems/step
    constexpr int NLD = (TOTS + 511) / 512;        // 6
    constexpr int TAIL = TOTS - (NLD - 1) * 512;   // 320
    __shared__ __align__(16) float s_in[16 * CHW]; // 12.8 KB; epilogue scratch too

    const int tid = threadIdx.x;
    int z = blockIdx.x;
    const int ocg = z & 3; z >>= 2;
    const int tile = z % NT;
    const int n = z / NT;
    const int th0 = (tile / NTW) * TH, tw0 = (tile % NTW) * TW;
    const int oc0 = ocg * 16;

    const int lane = tid & 63;
    const int wid8 = __builtin_amdgcn_readfirstlane(tid >> 6);  // 0..7
    const int widq = wid8 & 3;                     // oc quad
    const int half = wid8 >> 2;                    // ci half
    const int lx = lane & 7;
    const int ly = lane >> 3;
    const int px0 = lx * 2;

    const float* inb = in + (long)n * 64 * (S * S);
    // Wave-uniform weight base: [oc][ci][tap], oc stride 576.
    const float* wb = wgt + (long)(oc0 + widq * 4) * 576 + (half * 32) * 9;

    float acc[4][2];
#pragma unroll
    for (int k = 0; k < 4; ++k) { acc[k][0] = 0.f; acc[k][1] = 0.f; }

    for (int step = 0; step < 4; ++step) {
        __syncthreads();
        // Stage 16 channels (8 per ci-half) of the 10x18 halo tile.
#pragma unroll
        for (int j = 0; j < NLD; ++j) {
            int idx = tid + j * 512;
            bool slot = (j < NLD - 1) || (tid < TAIL);
            int t = slot ? idx : 0;
            int ch = t / 180;
            int rem = t - ch * 180;
            int r = rem / 18;
            int c = rem - r * 18;
            int gci = (ch >> 3) * 32 + step * 8 + (ch & 7);
            int gh = th0 + r - 1, gw = tw0 + c - 1;
            float v = 0.f;
            if (slot && (unsigned)gh < (unsigned)S && (unsigned)gw < (unsigned)S)
                v = inb[(long)gci * (S * S) + gh * S + gw];
            if (slot) s_in[ch * CHW + r * SROW + c] = v;
        }
        __syncthreads();
#pragma unroll
        for (int cc = 0; cc < 8; ++cc) {
            float xr[3][4];
#pragma unroll
            for (int r = 0; r < 3; ++r) {
                const float* rp =
                    &s_in[(half * 8 + cc) * CHW + (ly + r) * SROW + px0];
                float2 a = *(const float2*)rp;
                float2 b = *(const float2*)(rp + 2);
                xr[r][0] = a.x; xr[r][1] = a.y; xr[r][2] = b.x; xr[r][3] = b.y;
            }
            const float* wk0 = wb + (step * 8 + cc) * 9;
#pragma unroll
            for (int k = 0; k < 4; ++k) {
                const float* wk = wk0 + k * 576;
#pragma unroll
                for (int dh = 0; dh < 3; ++dh) {
                    float w0 = wk[dh * 3 + 0];
                    float w1 = wk[dh * 3 + 1];
                    float w2 = wk[dh * 3 + 2];
                    acc[k][0] += xr[dh][0] * w0 + xr[dh][1] * w1 + xr[dh][2] * w2;
                    acc[k][1] += xr[dh][1] * w0 + xr[dh][2] * w1 + xr[dh][3] * w2;
                }
            }
        }
    }

    // Cross-wave ci combine through LDS (conflict-free: stride-1 per j-slice).
    __syncthreads();
    if (half == 1) {
#pragma unroll
        for (int k = 0; k < 4; ++k) {
            s_in[(k * 2 + 0) * 256 + widq * 64 + lane] = acc[k][0];
            s_in[(k * 2 + 1) * 256 + widq * 64 + lane] = acc[k][1];
        }
    }
    __syncthreads();
    if (half == 0) {
        const int gy = th0 + ly, gx = tw0 + px0;
#pragma unroll
        for (int k = 0; k < 4; ++k) {
            float y0 = acc[k][0] + s_in[(k * 2 + 0) * 256 + widq * 64 + lane];
            float y1 = acc[k][1] + s_in[(k * 2 + 1) * 256 + widq * 64 + lane];
            float bv = bias[oc0 + widq * 4 + k];
            y0 += bv; y1 += bv;
            long po = ((long)(n * 64 + oc0 + widq * 4 + k)) * (S * S) +
                      gy * S + gx;
            if (VAR == 0) {
                y0 = y0 > 0.f ? y0 : 0.1f * y0;
                y1 = y1 > 0.f ? y1 : 0.1f * y1;
                float2 o; o.x = y0; o.y = y1;
                *(float2*)&outp[po] = o;
            } else if (VAR == 1) {
                float2 rv = *(const float2*)&res[po];
                float2 o; o.x = y0 + rv.x; o.y = y1 + rv.y;
                *(float2*)&outp[po] = o;
            } else {
                float2 rv = *(const float2*)&res[po];
                y0 += rv.x; y1 += rv.y;
                float m = fmaxf(y0, y1);
                float o = __shfl_xor(m, 8);    // partner row (ly^1)
                m = fmaxf(m, o);
                if ((ly & 1) == 0) {
                    constexpr int SP = S / 2;
                    long qo = ((long)(n * 64 + oc0 + widq * 4 + k)) *
                                  (SP * SP) +
                              (gy >> 1) * SP + (tw0 >> 1) + lx;
                    outp[qo] = m;
                }
            }
        }
    }
}

// 1x1 conv 64 -> 576 at 32x32. Block: 256 px, 8 oc. Weights in LDS.
__global__ __launch_bounds__(256) void conv1x1_k(
    const float* __restrict__ in, const float* __restrict__ w,
    const float* __restrict__ b, float* __restrict__ out) {
    __shared__ float s_in[32 * 256];
    __shared__ __align__(16) float s_w[64 * 8];
    const int tid = threadIdx.x;
    const int p0 = blockIdx.x * 256;
    const int cog = blockIdx.y;
    const int n = blockIdx.z;

    for (int idx = tid; idx < 512; idx += 256) {
        int j = idx >> 6;
        int ci = idx & 63;
        s_w[ci * 8 + j] = w[(long)cog * 512 + idx];
    }

    float acc[8];
#pragma unroll
    for (int i = 0; i < 8; ++i) acc[i] = b[cog * 8 + i];

    float pf[32];
#pragma unroll
    for (int i = 0; i < 32; ++i)
        pf[i] = in[(long)(n * 64 + i) * 1024 + p0 + tid];

    for (int chunk = 0; chunk < 64; chunk += 32) {
        __syncthreads();
#pragma unroll
        for (int i = 0; i < 32; ++i) s_in[i * 256 + tid] = pf[i];
        __syncthreads();
        if (chunk + 32 < 64) {
#pragma unroll
            for (int i = 0; i < 32; ++i)
                pf[i] = in[(long)(n * 64 + chunk + 32 + i) * 1024 + p0 + tid];
        }
#pragma unroll 4
        for (int ci = 0; ci < 32; ++ci) {
            float v = s_in[ci * 256 + tid];
            float4 w0 = *(const float4*)&s_w[(chunk + ci) * 8];
            float4 w1 = *(const float4*)&s_w[(chunk + ci) * 8 + 4];
            acc[0] += v * w0.x; acc[1] += v * w0.y;
            acc[2] += v * w0.z; acc[3] += v * w0.w;
            acc[4] += v * w1.x; acc[5] += v * w1.y;
            acc[6] += v * w1.z; acc[7] += v * w1.w;
        }
    }
#pragma unroll
    for (int oc = 0; oc < 8; ++oc)
        out[(long)(n * 576 + cog * 8 + oc) * 1024 + p0 + tid] = acc[oc];
}

// Fused bilinear x8 upsample + dynamic depthwise 3x3 (replicate pad on x).
__global__ __launch_bounds__(256) void dynconv_k(
    const float* __restrict__ x, const float* __restrict__ wt,
    float* __restrict__ out) {
    __shared__ __align__(16) float s_x[10 * 132];
    __shared__ float s_wt[9 * 60];                 // [tap][3r][20c], 0..17 used
    const int tid = threadIdx.x;
    const int tx = tid & 31;
    const int ty = tid >> 5;
    const int tw = (blockIdx.x & 1) * 128;
    const int th = (blockIdx.x >> 1) * 8;
    const int cz = blockIdx.y;

    const float* xb = x + (long)cz * 65536;
    for (int idx = tid; idx < 1300; idx += 256) {
        int r = idx / 130;
        int c = idx - r * 130;
        int gh = min(max(th + r - 1, 0), 255);
        int gw = min(max(tw + c - 1, 0), 255);
        s_x[r * 132 + c] = xb[gh * 256 + gw];
    }

    const int h0min = th / 8 - 1;                  // th multiple of 8
    const int w0min = tw / 8 - 1;
    const float* wtb = wt + (long)cz * 9 * 1024;
    for (int i = tid; i < 540; i += 256) {
        int tap = i / 60;
        int rem = i - tap * 60;
        int r = rem / 20;
        int c = rem - r * 20;
        if (c < 18) {
            int gr = min(max(h0min + r, 0), 31);
            int gc = min(max(w0min + c, 0), 31);
            s_wt[i] = wtb[tap * 1024 + gr * 32 + gc];
        }
    }

    const int h = th + ty;
    const int wbase = tw + tx * 4;
    float src_h = h * 0.125f - 0.4375f;
    int h0 = (int)floorf(src_h);
    float fh = src_h - (float)h0;
    int r0 = h0 - h0min;                           // 0 or 1
    float src_w = wbase * 0.125f - 0.4375f;
    int w0 = (int)floorf(src_w);
    float fw0 = src_w - (float)w0;
    int j = w0 - w0min;                            // 0..16

    __syncthreads();

    float vals[3][6];
#pragma unroll
    for (int r = 0; r < 3; ++r) {
        const float* rp = &s_x[(ty + r) * 132 + tx * 4];
        float4 a = *(const float4*)rp;
        float2 b = *(const float2*)(rp + 4);
        vals[r][0] = a.x; vals[r][1] = a.y; vals[r][2] = a.z;
        vals[r][3] = a.w; vals[r][4] = b.x; vals[r][5] = b.y;
    }

    float acc[4] = {0.f, 0.f, 0.f, 0.f};
#pragma unroll
    for (int dh = 0; dh < 3; ++dh)
#pragma unroll
        for (int dw = 0; dw < 3; ++dw) {
            const float* p = &s_wt[(dh * 3 + dw) * 60 + r0 * 20 + j];
            float t0 = p[0], t1 = p[1];
            float b0 = p[20], b1 = p[21];
            float c0 = t0 + fh * (b0 - t0);
            float c1 = t1 + fh * (b1 - t1);
            float d = c1 - c0;
#pragma unroll
            for (int jj = 0; jj < 4; ++jj) {
                float wv = c0 + (fw0 + 0.125f * jj) * d;
                acc[jj] += vals[dh][jj + dw] * wv;
            }
        }

    float4 o;
    o.x = acc[0]; o.y = acc[1]; o.z = acc[2]; o.w = acc[3];
    *(float4*)&out[(long)cz * 65536 + h * 256 + wbase] = o;
}

extern "C" void kernel_launch(void* const* d_in, const int* in_sizes, int n_in,
                              void* d_out, int out_size, void* d_ws, size_t ws_size,
                              hipStream_t stream) {
    const float* x    = (const float*)d_in[0];
    const float* b1w1 = (const float*)d_in[1];
    const float* b1b1 = (const float*)d_in[2];
    const float* b1w2 = (const float*)d_in[3];
    const float* b1b2 = (const float*)d_in[4];
    const float* b2w1 = (const float*)d_in[5];
    const float* b2b1 = (const float*)d_in[6];
    const float* b2w2 = (const float*)d_in[7];
    const float* b2b2 = (const float*)d_in[8];
    const float* tokw = (const float*)d_in[9];
    const float* tokb = (const float*)d_in[10];
    float* out = (float*)d_out;
    float* ws = (float*)d_ws;

    // Buffers (floats):
    float* X0 = ws;                 // 524288 [2,64,64,64]
    float* X1 = ws + 524288;        // 524288
    float* T  = ws + 1048576;       // 524288
    float* Pm = ws + 1572864;       // 131072 [2,64,32,32]
    float* Q  = ws + 1703936;       // 131072
    float* U  = ws + 1835008;       // 131072
    float* WT = ws + 1966080;       // 1179648 [2,576,32,32]

    const int WSZ = 64 * 64 * 9;

    avgpool4_k<<<2048, 256, 0, stream>>>(x, X0);

    // ---- S=64 resblocks: grid = 4ocg x 32tiles x 2n = 256 blocks x 512 ----
    conv3x3f_k<64, 0><<<256, 512, 0, stream>>>(X0, b1w1 + 0 * WSZ, b1b1 + 0,   nullptr, T);
    conv3x3f_k<64, 1><<<256, 512, 0, stream>>>(T,  b1w2 + 0 * WSZ, b1b2 + 0,   X0, X1);
    conv3x3f_k<64, 0><<<256, 512, 0, stream>>>(X1, b1w1 + 1 * WSZ, b1b1 + 64,  nullptr, T);
    conv3x3f_k<64, 1><<<256, 512, 0, stream>>>(T,  b1w2 + 1 * WSZ, b1b2 + 64,  X1, X0);
    conv3x3f_k<64, 0><<<256, 512, 0, stream>>>(X0, b1w1 + 2 * WSZ, b1b1 + 128, nullptr, T);
    conv3x3f_k<64, 2><<<256, 512, 0, stream>>>(T,  b1w2 + 2 * WSZ, b1b2 + 128, X0, Pm);

    // ---- S=32 resblocks: grid = 4ocg x 8tiles x 2n = 64 blocks x 512 ----
    conv3x3f_k<32, 0><<<64, 512, 0, stream>>>(Pm, b2w1 + 0 * WSZ, b2b1 + 0,   nullptr, U);
    conv3x3f_k<32, 1><<<64, 512, 0, stream>>>(U,  b2w2 + 0 * WSZ, b2b2 + 0,   Pm, Q);
    conv3x3f_k<32, 0><<<64, 512, 0, stream>>>(Q,  b2w1 + 1 * WSZ, b2b1 + 64,  nullptr, U);
    conv3x3f_k<32, 1><<<64, 512, 0, stream>>>(U,  b2w2 + 1 * WSZ, b2b2 + 64,  Q, Pm);
    conv3x3f_k<32, 0><<<64, 512, 0, stream>>>(Pm, b2w1 + 2 * WSZ, b2b1 + 128, nullptr, U);
    conv3x3f_k<32, 1><<<64, 512, 0, stream>>>(U,  b2w2 + 2 * WSZ, b2b2 + 128, Pm, Q);

    conv1x1_k<<<dim3(4, 72, 2), 256, 0, stream>>>(Q, tokw, tokb, WT);

    dynconv_k<<<dim3(64, 128), 256, 0, stream>>>(x, WT, out);
}

// Round 3
// 374.251 us; speedup vs baseline: 1.1999x; 1.1999x over previous
//
#include <hip/hip_runtime.h>

// ---------------------------------------------------------------------------
// IDynamicDWConv pipeline, fp32 end-to-end.
// R11: recover R9's proven high-occupancy kernels (R10's full-CI fusion
//     regressed: 64-block grids, 1 block/CU serial staging, s_load/ds_read
//     lgkmcnt serialization). New fusion that keeps occupancy: the 6 lrelu
//     combine dispatches are folded into the CONSUMER conv's staging loop
//     (conv3x3p_k: staged elem = lrelu(bias + sum_p P[p])), since that conv
//     re-stages the tensor anyway. Residual combs + maxpool_comb stay (their
//     outputs have 2 consumers). 27 -> 21 dispatches, conv kernels' compute
//     loop byte-identical to R9.
// ---------------------------------------------------------------------------

__global__ __launch_bounds__(256) void avgpool4_k(const float* __restrict__ x,
                                                  float* __restrict__ y) {
    int idx = blockIdx.x * 256 + threadIdx.x;      // 524288
    int wo = idx & 63;
    int ho = (idx >> 6) & 63;
    int cz = idx >> 12;
    const float* base = x + ((long)cz * 256 + ho * 4) * 256 + wo * 4;
    float s = 0.f;
#pragma unroll
    for (int r = 0; r < 4; ++r) {
        float4 v = *(const float4*)(base + r * 256);
        s += v.x + v.y + v.z + v.w;
    }
    y[idx] = s * 0.0625f;
}

// K-split direct 3x3 conv (zero-pad SAME). Block: 256 thr = 4 waves; each
// wave = full 16x16 tile for a 4-oc slice; lane = 4 w-px x 4 oc.
// Partials out: [ks][n][oc][S][S].
template <int S, int CIB>
__global__ __launch_bounds__(256, 2) void conv3x3s_k(
    const float* __restrict__ in, const float* __restrict__ wgt,
    float* __restrict__ outp) {
    constexpr int KSN = 64 / CIB;
    constexpr int T = 16;
    constexpr int NT1 = S / T;
    constexpr int NT = NT1 * NT1;
    constexpr int HW = T + 2;                      // 18 cols used
    constexpr int SROW = 20;                       // padded row stride
    constexpr int TOT = CIB * 18 * HW;
    constexpr int NLD = (TOT + 255) / 256;
    constexpr int TAIL = TOT - (NLD - 1) * 256;
    __shared__ __align__(16) float s_in[CIB * 18 * SROW];

    const int tid = threadIdx.x;
    int z = blockIdx.x;
    const int ks = z % KSN; z /= KSN;
    const int ocg = z & 3; z >>= 2;
    const int tile = z % NT;
    const int n = z / NT;
    const int th0 = (tile / NT1) * T, tw0 = (tile % NT1) * T;
    const int oc0 = ocg * 16;

    // Input tile staging: flat coalesced burst, zero OOB.
    const float* inb = in + ((long)n * 64 + ks * CIB) * (S * S);
#pragma unroll
    for (int j = 0; j < NLD; ++j) {
        int idx = tid + j * 256;
        bool slot = (j < NLD - 1) || (tid < TAIL);
        int t = slot ? idx : 0;
        int ci = t / (18 * HW);
        int rem = t - ci * (18 * HW);
        int r = rem / HW;
        int c = rem - r * HW;
        int gh = th0 + r - 1, gw = tw0 + c - 1;
        float v = 0.f;
        if (slot && (unsigned)gh < (unsigned)S && (unsigned)gw < (unsigned)S)
            v = inb[ci * (S * S) + gh * S + gw];
        if (slot) s_in[ci * (18 * SROW) + r * SROW + c] = v;
    }
    __syncthreads();

    const int lane = tid & 63;
    const int wid = __builtin_amdgcn_readfirstlane(tid >> 6);  // 4-oc slice
    const int lx = lane & 3;                       // 4 strips across 16
    const int ly = lane >> 2;                      // 0..15 row
    const int px0 = lx * 4;

    // Wave-uniform weight base: [oc][ci][tap], oc stride 576.
    const float* wb = wgt + (long)(oc0 + wid * 4) * 576 + ks * (CIB * 9);

    float acc[4][4];
#pragma unroll
    for (int k = 0; k < 4; ++k)
#pragma unroll
        for (int p = 0; p < 4; ++p) acc[k][p] = 0.f;

#pragma unroll
    for (int ci = 0; ci < CIB; ++ci) {
        float xr[3][6];
#pragma unroll
        for (int r = 0; r < 3; ++r) {
            const float* rp = &s_in[ci * (18 * SROW) + (ly + r) * SROW + px0];
            float4 a = *(const float4*)rp;
            float2 b = *(const float2*)(rp + 4);
            xr[r][0] = a.x; xr[r][1] = a.y; xr[r][2] = a.z;
            xr[r][3] = a.w; xr[r][4] = b.x; xr[r][5] = b.y;
        }
#pragma unroll
        for (int k = 0; k < 4; ++k) {
            const float* wk = wb + k * 576 + ci * 9;
#pragma unroll
            for (int dh = 0; dh < 3; ++dh) {
                float w0 = wk[dh * 3 + 0];
                float w1 = wk[dh * 3 + 1];
                float w2 = wk[dh * 3 + 2];
#pragma unroll
                for (int p = 0; p < 4; ++p)
                    acc[k][p] += xr[dh][p] * w0 + xr[dh][p + 1] * w1 +
                                 xr[dh][p + 2] * w2;
            }
        }
    }

    const int gy = th0 + ly, gx = tw0 + px0;
    const long pstride = (long)2 * 64 * S * S;
    long off0 = ks * pstride +
                ((long)(n * 64 + oc0 + wid * 4)) * (S * S) + gy * S + gx;
#pragma unroll
    for (int k = 0; k < 4; ++k) {
        float4 v;
        v.x = acc[k][0]; v.y = acc[k][1]; v.z = acc[k][2]; v.w = acc[k][3];
        *(float4*)&outp[off0 + (long)k * (S * S)] = v;
    }
}

// Same conv, but the input tensor is materialized on the fly from the
// previous conv's partials: staged elem = lrelu(bias[c] + sum_p P[p][...]).
// Folds the standalone lrelu-comb dispatch into the consumer's staging.
template <int S, int CIB, int NP>
__global__ __launch_bounds__(256, 2) void conv3x3p_k(
    const float* __restrict__ Pin, const float* __restrict__ bias,
    const float* __restrict__ wgt, float* __restrict__ outp) {
    constexpr int KSN = 64 / CIB;
    constexpr int T = 16;
    constexpr int NT1 = S / T;
    constexpr int NT = NT1 * NT1;
    constexpr int HW = T + 2;
    constexpr int SROW = 20;
    constexpr int TOT = CIB * 18 * HW;
    constexpr int NLD = (TOT + 255) / 256;
    constexpr int TAIL = TOT - (NLD - 1) * 256;
    __shared__ __align__(16) float s_in[CIB * 18 * SROW];

    const int tid = threadIdx.x;
    int z = blockIdx.x;
    const int ks = z % KSN; z /= KSN;
    const int ocg = z & 3; z >>= 2;
    const int tile = z % NT;
    const int n = z / NT;
    const int th0 = (tile / NT1) * T, tw0 = (tile % NT1) * T;
    const int oc0 = ocg * 16;

    // Staging with on-the-fly combine: in[c,h,w] = lrelu(b[c]+sum_p P).
    const long pstr = (long)2 * 64 * S * S;
    const float* pb = Pin + (long)n * 64 * (S * S);
#pragma unroll
    for (int j = 0; j < NLD; ++j) {
        int idx = tid + j * 256;
        bool slot = (j < NLD - 1) || (tid < TAIL);
        int t = slot ? idx : 0;
        int ci = t / (18 * HW);
        int rem = t - ci * (18 * HW);
        int r = rem / HW;
        int c = rem - r * HW;
        int gci = ks * CIB + ci;
        int gh = th0 + r - 1, gw = tw0 + c - 1;
        float v = 0.f;
        if (slot && (unsigned)gh < (unsigned)S && (unsigned)gw < (unsigned)S) {
            long o = (long)gci * (S * S) + gh * S + gw;
            v = bias[gci];
#pragma unroll
            for (int p = 0; p < NP; ++p) v += pb[o + p * pstr];
            v = v > 0.f ? v : 0.1f * v;
        }
        if (slot) s_in[ci * (18 * SROW) + r * SROW + c] = v;
    }
    __syncthreads();

    const int lane = tid & 63;
    const int wid = __builtin_amdgcn_readfirstlane(tid >> 6);
    const int lx = lane & 3;
    const int ly = lane >> 2;
    const int px0 = lx * 4;

    const float* wb = wgt + (long)(oc0 + wid * 4) * 576 + ks * (CIB * 9);

    float acc[4][4];
#pragma unroll
    for (int k = 0; k < 4; ++k)
#pragma unroll
        for (int p = 0; p < 4; ++p) acc[k][p] = 0.f;

#pragma unroll
    for (int ci = 0; ci < CIB; ++ci) {
        float xr[3][6];
#pragma unroll
        for (int r = 0; r < 3; ++r) {
            const float* rp = &s_in[ci * (18 * SROW) + (ly + r) * SROW + px0];
            float4 a = *(const float4*)rp;
            float2 b = *(const float2*)(rp + 4);
            xr[r][0] = a.x; xr[r][1] = a.y; xr[r][2] = a.z;
            xr[r][3] = a.w; xr[r][4] = b.x; xr[r][5] = b.y;
        }
#pragma unroll
        for (int k = 0; k < 4; ++k) {
            const float* wk = wb + k * 576 + ci * 9;
#pragma unroll
            for (int dh = 0; dh < 3; ++dh) {
                float w0 = wk[dh * 3 + 0];
                float w1 = wk[dh * 3 + 1];
                float w2 = wk[dh * 3 + 2];
#pragma unroll
                for (int p = 0; p < 4; ++p)
                    acc[k][p] += xr[dh][p] * w0 + xr[dh][p + 1] * w1 +
                                 xr[dh][p + 2] * w2;
            }
        }
    }

    const int gy = th0 + ly, gx = tw0 + px0;
    long off0 = ks * pstr +
                ((long)(n * 64 + oc0 + wid * 4)) * (S * S) + gy * S + gx;
#pragma unroll
    for (int k = 0; k < 4; ++k) {
        float4 v;
        v.x = acc[k][0]; v.y = acc[k][1]; v.z = acc[k][2]; v.w = acc[k][3];
        *(float4*)&outp[off0 + (long)k * (S * S)] = v;
    }
}

// Combine NP partials + bias (+lrelu / +res), float4 per thread.
template <int NP, int SSLOG, bool LRELU, bool RES>
__global__ __launch_bounds__(256) void comb_k(
    const float* __restrict__ P, const float* __restrict__ bias,
    const float* __restrict__ res, float* __restrict__ out) {
    const long pstride = (long)2 * 64 << SSLOG;
    long base = ((long)blockIdx.x * 256 + threadIdx.x) * 4;
    int c = (int)((base >> SSLOG) & 63);
    float4 v = *(const float4*)&P[base];
#pragma unroll
    for (int p = 1; p < NP; ++p) {
        float4 u = *(const float4*)&P[base + p * pstride];
        v.x += u.x; v.y += u.y; v.z += u.z; v.w += u.w;
    }
    float b = bias[c];
    v.x += b; v.y += b; v.z += b; v.w += b;
    if (LRELU) {
        v.x = v.x > 0.f ? v.x : 0.1f * v.x;
        v.y = v.y > 0.f ? v.y : 0.1f * v.y;
        v.z = v.z > 0.f ? v.z : 0.1f * v.z;
        v.w = v.w > 0.f ? v.w : 0.1f * v.w;
    }
    if (RES) {
        float4 r = *(const float4*)&res[base];
        v.x += r.x; v.y += r.y; v.z += r.z; v.w += r.w;
    }
    *(float4*)&out[base] = v;
}

// maxpool2 fused with final combine: y = sumNP(P) + bias + res, pool 2x2.
template <int NP>
__global__ __launch_bounds__(256) void maxpool_comb_k(
    const float* __restrict__ Pb, const float* __restrict__ bias,
    const float* __restrict__ res, float* __restrict__ P) {
    int idx = blockIdx.x * 256 + threadIdx.x;      // 131072
    int wo = idx & 31;
    int ho = (idx >> 5) & 31;
    int cz = idx >> 10;
    float bch = bias[cz & 63];
    float m = -3.4e38f;
#pragma unroll
    for (int dh = 0; dh < 2; ++dh)
#pragma unroll
        for (int dw = 0; dw < 2; ++dw) {
            long off = ((long)cz * 64 + ho * 2 + dh) * 64 + wo * 2 + dw;
            float y = bch + res[off];
#pragma unroll
            for (int p = 0; p < NP; ++p) y += Pb[off + (long)p * 524288];
            m = fmaxf(m, y);
        }
    P[idx] = m;
}

// 1x1 conv 64 -> 576 at 32x32. Block: 256 px, 8 oc. Weights in LDS.
__global__ __launch_bounds__(256) void conv1x1_k(
    const float* __restrict__ in, const float* __restrict__ w,
    const float* __restrict__ b, float* __restrict__ out) {
    __shared__ float s_in[32 * 256];
    __shared__ __align__(16) float s_w[64 * 8];
    const int tid = threadIdx.x;
    const int p0 = blockIdx.x * 256;
    const int cog = blockIdx.y;
    const int n = blockIdx.z;

    for (int idx = tid; idx < 512; idx += 256) {
        int j = idx >> 6;
        int ci = idx & 63;
        s_w[ci * 8 + j] = w[(long)cog * 512 + idx];
    }

    float acc[8];
#pragma unroll
    for (int i = 0; i < 8; ++i) acc[i] = b[cog * 8 + i];

    float pf[32];
#pragma unroll
    for (int i = 0; i < 32; ++i)
        pf[i] = in[(long)(n * 64 + i) * 1024 + p0 + tid];

    for (int chunk = 0; chunk < 64; chunk += 32) {
        __syncthreads();
#pragma unroll
        for (int i = 0; i < 32; ++i) s_in[i * 256 + tid] = pf[i];
        __syncthreads();
        if (chunk + 32 < 64) {
#pragma unroll
            for (int i = 0; i < 32; ++i)
                pf[i] = in[(long)(n * 64 + chunk + 32 + i) * 1024 + p0 + tid];
        }
#pragma unroll 4
        for (int ci = 0; ci < 32; ++ci) {
            float v = s_in[ci * 256 + tid];
            float4 w0 = *(const float4*)&s_w[(chunk + ci) * 8];
            float4 w1 = *(const float4*)&s_w[(chunk + ci) * 8 + 4];
            acc[0] += v * w0.x; acc[1] += v * w0.y;
            acc[2] += v * w0.z; acc[3] += v * w0.w;
            acc[4] += v * w1.x; acc[5] += v * w1.y;
            acc[6] += v * w1.z; acc[7] += v * w1.w;
        }
    }
#pragma unroll
    for (int oc = 0; oc < 8; ++oc)
        out[(long)(n * 576 + cog * 8 + oc) * 1024 + p0 + tid] = acc[oc];
}

// Fused bilinear x8 upsample + dynamic depthwise 3x3 (replicate pad on x).
__global__ __launch_bounds__(256) void dynconv_k(
    const float* __restrict__ x, const float* __restrict__ wt,
    float* __restrict__ out) {
    __shared__ __align__(16) float s_x[10 * 132];
    __shared__ float s_wt[9 * 60];                 // [tap][3r][20c], 0..17 used
    const int tid = threadIdx.x;
    const int tx = tid & 31;
    const int ty = tid >> 5;
    const int tw = (blockIdx.x & 1) * 128;
    const int th = (blockIdx.x >> 1) * 8;
    const int cz = blockIdx.y;

    const float* xb = x + (long)cz * 65536;
    for (int idx = tid; idx < 1300; idx += 256) {
        int r = idx / 130;
        int c = idx - r * 130;
        int gh = min(max(th + r - 1, 0), 255);
        int gw = min(max(tw + c - 1, 0), 255);
        s_x[r * 132 + c] = xb[gh * 256 + gw];
    }

    const int h0min = th / 8 - 1;                  // th multiple of 8
    const int w0min = tw / 8 - 1;
    const float* wtb = wt + (long)cz * 9 * 1024;
    for (int i = tid; i < 540; i += 256) {
        int tap = i / 60;
        int rem = i - tap * 60;
        int r = rem / 20;
        int c = rem - r * 20;
        if (c < 18) {
            int gr = min(max(h0min + r, 0), 31);
            int gc = min(max(w0min + c, 0), 31);
            s_wt[i] = wtb[tap * 1024 + gr * 32 + gc];
        }
    }

    const int h = th + ty;
    const int wbase = tw + tx * 4;
    float src_h = h * 0.125f - 0.4375f;
    int h0 = (int)floorf(src_h);
    float fh = src_h - (float)h0;
    int r0 = h0 - h0min;                           // 0 or 1
    float src_w = wbase * 0.125f - 0.4375f;
    int w0 = (int)floorf(src_w);
    float fw0 = src_w - (float)w0;
    int j = w0 - w0min;                            // 0..16

    __syncthreads();

    float vals[3][6];
#pragma unroll
    for (int r = 0; r < 3; ++r) {
        const float* rp = &s_x[(ty + r) * 132 + tx * 4];
        float4 a = *(const float4*)rp;
        float2 b = *(const float2*)(rp + 4);
        vals[r][0] = a.x; vals[r][1] = a.y; vals[r][2] = a.z;
        vals[r][3] = a.w; vals[r][4] = b.x; vals[r][5] = b.y;
    }

    float acc[4] = {0.f, 0.f, 0.f, 0.f};
#pragma unroll
    for (int dh = 0; dh < 3; ++dh)
#pragma unroll
        for (int dw = 0; dw < 3; ++dw) {
            const float* p = &s_wt[(dh * 3 + dw) * 60 + r0 * 20 + j];
            float t0 = p[0], t1 = p[1];
            float b0 = p[20], b1 = p[21];
            float c0 = t0 + fh * (b0 - t0);
            float c1 = t1 + fh * (b1 - t1);
            float d = c1 - c0;
#pragma unroll
            for (int jj = 0; jj < 4; ++jj) {
                float wv = c0 + (fw0 + 0.125f * jj) * d;
                acc[jj] += vals[dh][jj + dw] * wv;
            }
        }

    float4 o;
    o.x = acc[0]; o.y = acc[1]; o.z = acc[2]; o.w = acc[3];
    *(float4*)&out[(long)cz * 65536 + h * 256 + wbase] = o;
}

extern "C" void kernel_launch(void* const* d_in, const int* in_sizes, int n_in,
                              void* d_out, int out_size, void* d_ws, size_t ws_size,
                              hipStream_t stream) {
    const float* x    = (const float*)d_in[0];
    const float* b1w1 = (const float*)d_in[1];
    const float* b1b1 = (const float*)d_in[2];
    const float* b1w2 = (const float*)d_in[3];
    const float* b1b2 = (const float*)d_in[4];
    const float* b2w1 = (const float*)d_in[5];
    const float* b2b1 = (const float*)d_in[6];
    const float* b2w2 = (const float*)d_in[7];
    const float* b2b2 = (const float*)d_in[8];
    const float* tokw = (const float*)d_in[9];
    const float* tokb = (const float*)d_in[10];
    float* out = (float*)d_out;
    float* ws = (float*)d_ws;

    // Buffers (floats):
    float* X0 = ws;                 // 524288 [2,64,64,64]
    float* X1 = ws + 524288;        // 524288
    float* P  = ws + 1048576;       // 2097152 partials A (4x524288 / 8x131072)
    float* P2 = ws + 3145728;       // 2097152 partials B
    float* Pm = ws + 5242880;       // 131072 [2,64,32,32]
    float* Q  = ws + 5373952;       // 131072
    float* WT = ws + 5505024;       // 1179648 [2,576,32,32]

    const int WSZ = 64 * 64 * 9;

    avgpool4_k<<<2048, 256, 0, stream>>>(x, X0);

    // ---- S=64 resblocks: convA (plain) -> P; convB (fold lrelu-comb from P)
    //      -> P2; residual comb / maxpool_comb from P2. ----
    conv3x3s_k<64, 16><<<512, 256, 0, stream>>>(X0, b1w1 + 0 * WSZ, P);
    conv3x3p_k<64, 16, 4><<<512, 256, 0, stream>>>(P, b1b1 + 0, b1w2 + 0 * WSZ, P2);
    comb_k<4, 12, false, true ><<<512, 256, 0, stream>>>(P2, b1b2 + 0, X0, X1);

    conv3x3s_k<64, 16><<<512, 256, 0, stream>>>(X1, b1w1 + 1 * WSZ, P);
    conv3x3p_k<64, 16, 4><<<512, 256, 0, stream>>>(P, b1b1 + 64, b1w2 + 1 * WSZ, P2);
    comb_k<4, 12, false, true ><<<512, 256, 0, stream>>>(P2, b1b2 + 64, X1, X0);

    conv3x3s_k<64, 16><<<512, 256, 0, stream>>>(X0, b1w1 + 2 * WSZ, P);
    conv3x3p_k<64, 16, 4><<<512, 256, 0, stream>>>(P, b1b1 + 128, b1w2 + 2 * WSZ, P2);
    maxpool_comb_k<4><<<512, 256, 0, stream>>>(P2, b1b2 + 128, X0, Pm);

    // ---- S=32 resblocks ----
    conv3x3s_k<32, 8><<<256, 256, 0, stream>>>(Pm, b2w1 + 0 * WSZ, P);
    conv3x3p_k<32, 8, 8><<<256, 256, 0, stream>>>(P, b2b1 + 0, b2w2 + 0 * WSZ, P2);
    comb_k<8, 10, false, true ><<<128, 256, 0, stream>>>(P2, b2b2 + 0, Pm, Q);

    conv3x3s_k<32, 8><<<256, 256, 0, stream>>>(Q, b2w1 + 1 * WSZ, P);
    conv3x3p_k<32, 8, 8><<<256, 256, 0, stream>>>(P, b2b1 + 64, b2w2 + 1 * WSZ, P2);
    comb_k<8, 10, false, true ><<<128, 256, 0, stream>>>(P2, b2b2 + 64, Q, Pm);

    conv3x3s_k<32, 8><<<256, 256, 0, stream>>>(Pm, b2w1 + 2 * WSZ, P);
    conv3x3p_k<32, 8, 8><<<256, 256, 0, stream>>>(P, b2b1 + 128, b2w2 + 2 * WSZ, P2);
    comb_k<8, 10, false, true ><<<128, 256, 0, stream>>>(P2, b2b2 + 128, Pm, Q);

    conv1x1_k<<<dim3(4, 72, 2), 256, 0, stream>>>(Q, tokw, tokb, WT);

    dynconv_k<<<dim3(64, 128), 256, 0, stream>>>(x, WT, out);
}